// Round 1
// baseline (15472.223 us; speedup 1.0000x reference)
//
#include <hip/hip_runtime.h>

// Problem constants
#define BB 512   // batch
#define TT 512   // time
#define FF 64    // input features (layer 1)
#define HH 128   // hidden
#define G4 512   // 4*H gates
#define NCLS 10

__device__ __forceinline__ float sigf(float x) { return 1.0f / (1.0f + __expf(-x)); }
__device__ __forceinline__ float tanhfast(float x) { return 2.0f / (1.0f + __expf(-2.0f * x)) - 1.0f; }

// ---------------------------------------------------------------------------
// Layer-1 scan, fused input projection. One block = 2 batch rows, 512 threads.
// Thread g owns gate g: holds W1_ih[g,0:64] + W1_hh[g,0:128] in 192 VGPRs.
// h (and staged x) live in LDS; c lives in registers of threads 0..255.
// ---------------------------------------------------------------------------
__global__ __launch_bounds__(512, 2) void scan1_kernel(
    const float* __restrict__ x, const float* __restrict__ w_ih,
    const float* __restrict__ w_hh, const float* __restrict__ b_ih,
    const float* __restrict__ b_hh, float* __restrict__ out1c,
    float* __restrict__ h1s, float* __restrict__ c1s,
    int t0, int Tc, int first)
{
    const int g = threadIdx.x;           // gate index 0..511
    const int r0 = blockIdx.x * 2;       // batch rows r0, r0+1

    __shared__ __align__(16) float inbuf[2][192];   // [row][0:64 = x_t, 64:192 = h_{t-1}]
    __shared__ __align__(16) float abuf[2][512];    // activated gate values

    // --- weights into registers (concatenated [w_ih row | w_hh row]) ---
    float4 wv[48];
    {
        const float4* wi = (const float4*)(w_ih + (size_t)g * FF);
        #pragma unroll
        for (int q = 0; q < 16; q++) wv[q] = wi[q];
        const float4* wh = (const float4*)(w_hh + (size_t)g * HH);
        #pragma unroll
        for (int q = 0; q < 32; q++) wv[16 + q] = wh[q];
    }
    const float bias = b_ih[g] + b_hh[g];

    // --- state init / restore ---
    const int row = g >> 7, j = g & 127;    // meaningful for g < 256
    float c = 0.0f;
    if (g < 256) {
        const int b = r0 + row;
        if (first) {
            inbuf[row][64 + j] = 0.0f;
        } else {
            c = c1s[b * HH + j];
            inbuf[row][64 + j] = h1s[b * HH + j];
        }
    }
    __syncthreads();

    for (int tl = 0; tl < Tc; tl++) {
        const int t = t0 + tl;
        // stage x_t for both rows (threads 0..127)
        if (g < 128) {
            const int rr = g >> 6, i = g & 63;
            inbuf[rr][i] = x[(size_t)(r0 + rr) * TT * FF + (size_t)t * FF + i];
        }
        __syncthreads();

        // gate pre-activations: 192-dot per row (LDS broadcast reads)
        float acc0 = bias, acc1 = bias;
        const float4* in0 = (const float4*)(&inbuf[0][0]);
        const float4* in1 = (const float4*)(&inbuf[1][0]);
        #pragma unroll
        for (int q = 0; q < 48; q++) {
            const float4 w = wv[q];
            const float4 a0 = in0[q];
            const float4 a1 = in1[q];
            acc0 += w.x * a0.x + w.y * a0.y + w.z * a0.z + w.w * a0.w;
            acc1 += w.x * a1.x + w.y * a1.y + w.z * a1.z + w.w * a1.w;
        }
        const int type = g >> 7;  // 0:i 1:f 2:g 3:o
        abuf[0][g] = (type == 2) ? tanhfast(acc0) : sigf(acc0);
        abuf[1][g] = (type == 2) ? tanhfast(acc1) : sigf(acc1);
        __syncthreads();

        // state update (threads 0..255: one (row, hidden-unit) each)
        if (g < 256) {
            const float iv = abuf[row][j];
            const float fv = abuf[row][128 + j];
            const float gv = abuf[row][256 + j];
            const float ov = abuf[row][384 + j];
            c = fv * c + iv * gv;
            const float h = ov * tanhfast(c);
            inbuf[row][64 + j] = h;
            out1c[(size_t)(r0 + row) * Tc * HH + (size_t)tl * HH + j] = h;
        }
        __syncthreads();
    }

    // save state for next chunk
    if (g < 256) {
        const int b = r0 + row;
        c1s[b * HH + j] = c;
        h1s[b * HH + j] = inbuf[row][64 + j];
    }
}

// ---------------------------------------------------------------------------
// xp2 = out1_chunk @ W2_ih^T + (b2_ih + b2_hh). Thread g owns gate g's W row
// in 128 VGPRs; rows staged 2-at-a-time through LDS (broadcast).
// ---------------------------------------------------------------------------
__global__ __launch_bounds__(512, 2) void proj2_kernel(
    const float* __restrict__ out1c, const float* __restrict__ w_ih,
    const float* __restrict__ b_ih, const float* __restrict__ b_hh,
    float* __restrict__ xp2, int Tc)
{
    const int g = threadIdx.x;
    float4 wv[32];
    {
        const float4* wi = (const float4*)(w_ih + (size_t)g * HH);
        #pragma unroll
        for (int q = 0; q < 32; q++) wv[q] = wi[q];
    }
    const float bias = b_ih[g] + b_hh[g];

    __shared__ __align__(16) float rowbuf[2][HH];

    const int nrows = BB * Tc;   // even
    for (int r = blockIdx.x * 2; r < nrows; r += gridDim.x * 2) {
        if (g < 256) {
            const int rr = g >> 7, i = g & 127;
            rowbuf[rr][i] = out1c[(size_t)(r + rr) * HH + i];
        }
        __syncthreads();
        float acc0 = 0.0f, acc1 = 0.0f;
        const float4* i0 = (const float4*)(&rowbuf[0][0]);
        const float4* i1 = (const float4*)(&rowbuf[1][0]);
        #pragma unroll
        for (int q = 0; q < 32; q++) {
            const float4 w = wv[q];
            const float4 a0 = i0[q];
            const float4 a1 = i1[q];
            acc0 += w.x * a0.x + w.y * a0.y + w.z * a0.z + w.w * a0.w;
            acc1 += w.x * a1.x + w.y * a1.y + w.z * a1.z + w.w * a1.w;
        }
        xp2[(size_t)r * G4 + g] = acc0 + bias;
        xp2[(size_t)(r + 1) * G4 + g] = acc1 + bias;
        __syncthreads();
    }
}

// ---------------------------------------------------------------------------
// Layer-2 scan from precomputed xp2. Same structure as scan1, K=128 only.
// ---------------------------------------------------------------------------
__global__ __launch_bounds__(512, 2) void scan2_kernel(
    const float* __restrict__ xp2, const float* __restrict__ w_hh,
    float* __restrict__ h2s, float* __restrict__ c2s,
    int Tc, int first)
{
    const int g = threadIdx.x;
    const int r0 = blockIdx.x * 2;

    __shared__ __align__(16) float hbuf[2][HH];
    __shared__ __align__(16) float abuf[2][512];

    float4 wv[32];
    {
        const float4* wh = (const float4*)(w_hh + (size_t)g * HH);
        #pragma unroll
        for (int q = 0; q < 32; q++) wv[q] = wh[q];
    }

    const int row = g >> 7, j = g & 127;
    float c = 0.0f;
    if (g < 256) {
        const int b = r0 + row;
        if (first) {
            hbuf[row][j] = 0.0f;
        } else {
            c = c2s[b * HH + j];
            hbuf[row][j] = h2s[b * HH + j];
        }
    }
    __syncthreads();

    for (int tl = 0; tl < Tc; tl++) {
        // issue global loads early; they are summed in at the end of the dot
        const float xv0 = xp2[(size_t)(r0 * Tc + tl) * G4 + g];
        const float xv1 = xp2[(size_t)((r0 + 1) * Tc + tl) * G4 + g];
        float acc0 = 0.0f, acc1 = 0.0f;
        const float4* h0p = (const float4*)(&hbuf[0][0]);
        const float4* h1p = (const float4*)(&hbuf[1][0]);
        #pragma unroll
        for (int q = 0; q < 32; q++) {
            const float4 w = wv[q];
            const float4 a0 = h0p[q];
            const float4 a1 = h1p[q];
            acc0 += w.x * a0.x + w.y * a0.y + w.z * a0.z + w.w * a0.w;
            acc1 += w.x * a1.x + w.y * a1.y + w.z * a1.z + w.w * a1.w;
        }
        acc0 += xv0;
        acc1 += xv1;
        const int type = g >> 7;
        abuf[0][g] = (type == 2) ? tanhfast(acc0) : sigf(acc0);
        abuf[1][g] = (type == 2) ? tanhfast(acc1) : sigf(acc1);
        __syncthreads();

        if (g < 256) {
            const float iv = abuf[row][j];
            const float fv = abuf[row][128 + j];
            const float gv = abuf[row][256 + j];
            const float ov = abuf[row][384 + j];
            c = fv * c + iv * gv;
            hbuf[row][j] = ov * tanhfast(c);
        }
        __syncthreads();
    }

    if (g < 256) {
        const int b = r0 + row;
        c2s[b * HH + j] = c;
        h2s[b * HH + j] = hbuf[row][j];
    }
}

// ---------------------------------------------------------------------------
// logits = h2_last @ w_fc^T + b_fc; sigmoid.
// ---------------------------------------------------------------------------
__global__ void final_kernel(const float* __restrict__ h2s,
                             const float* __restrict__ w_fc,
                             const float* __restrict__ b_fc,
                             float* __restrict__ out)
{
    const int idx = blockIdx.x * blockDim.x + threadIdx.x;
    if (idx >= BB * NCLS) return;
    const int b = idx / NCLS, cls = idx % NCLS;
    const float* h = h2s + (size_t)b * HH;
    const float* w = w_fc + (size_t)cls * HH;
    float acc = b_fc[cls];
    #pragma unroll 8
    for (int k = 0; k < HH; k++) acc += h[k] * w[k];
    out[idx] = sigf(acc);
}

extern "C" void kernel_launch(void* const* d_in, const int* in_sizes, int n_in,
                              void* d_out, int out_size, void* d_ws, size_t ws_size,
                              hipStream_t stream)
{
    const float* x     = (const float*)d_in[0];
    const float* w1_ih = (const float*)d_in[1];
    const float* w1_hh = (const float*)d_in[2];
    const float* b1_ih = (const float*)d_in[3];
    const float* b1_hh = (const float*)d_in[4];
    const float* w2_ih = (const float*)d_in[5];
    const float* w2_hh = (const float*)d_in[6];
    const float* b2_ih = (const float*)d_in[7];
    const float* b2_hh = (const float*)d_in[8];
    const float* w_fc  = (const float*)d_in[9];
    const float* b_fc  = (const float*)d_in[10];
    float* out = (float*)d_out;

    // workspace layout: [h1|c1|h2|c2 | out1_chunk | xp2_chunk]
    char* ws = (char*)d_ws;
    const size_t state_bytes = (size_t)BB * HH * sizeof(float);   // 256 KB each
    float* h1s = (float*)ws; ws += state_bytes;
    float* c1s = (float*)ws; ws += state_bytes;
    float* h2s = (float*)ws; ws += state_bytes;
    float* c2s = (float*)ws; ws += state_bytes;

    // pick largest chunk that fits in ws (deterministic: ws_size fixed per run)
    int Tc = 64;
    while (Tc > 4 &&
           4 * state_bytes + (size_t)BB * Tc * (HH + G4) * sizeof(float) > ws_size)
        Tc >>= 1;

    float* out1c = (float*)ws; ws += (size_t)BB * Tc * HH * sizeof(float);
    float* xp2c  = (float*)ws;

    const int nch = TT / Tc;
    for (int ci = 0; ci < nch; ci++) {
        scan1_kernel<<<256, 512, 0, stream>>>(x, w1_ih, w1_hh, b1_ih, b1_hh,
                                              out1c, h1s, c1s, ci * Tc, Tc, ci == 0);
        proj2_kernel<<<256, 512, 0, stream>>>(out1c, w2_ih, b2_ih, b2_hh, xp2c, Tc);
        scan2_kernel<<<256, 512, 0, stream>>>(xp2c, w2_hh, h2s, c2s, Tc, ci == 0);
    }
    final_kernel<<<(BB * NCLS + 255) / 256, 256, 0, stream>>>(h2s, w_fc, b_fc, out);
}

// Round 2
// 4564.606 us; speedup vs baseline: 3.3896x; 3.3896x over previous
//
#include <hip/hip_runtime.h>

// Problem constants
#define BB 512   // batch
#define TT 512   // time
#define FF 64    // input features (layer 1)
#define HH 128   // hidden
#define G4 512   // 4*H gates
#define NCLS 10

__device__ __forceinline__ float sigf(float x) { return 1.0f / (1.0f + __expf(-x)); }
__device__ __forceinline__ float tanhfast(float x) { return 2.0f / (1.0f + __expf(-2.0f * x)) - 1.0f; }

// ---------------------------------------------------------------------------
// xp = in_rows @ W^T + (b_a + b_b).  K = 64 (layer1 x-proj) or 128 (layer2).
// 1024 threads: thread t -> (gate g = t>>1, half s = t&1). Each thread holds
// K/2 weight floats in registers (<=16 float4 = 64 VGPRs). Rows broadcast
// 2-at-a-time through LDS; lane-pair partial dots combined via shfl_xor.
// Row r maps to (b = r>>log2Tc, tl = r&(Tc-1)); element addr
// in[(b*inT + t0 + tl)*K + i]  -- covers both the strided x chunk (inT=TT)
// and the compact out1 chunk (inT=Tc, t0=0).
// ---------------------------------------------------------------------------
template <int K>
__global__ __launch_bounds__(1024, 1) void xp_kernel(
    const float* __restrict__ in, const float* __restrict__ w,
    const float* __restrict__ b_a, const float* __restrict__ b_b,
    float* __restrict__ xp, int Tc, int log2Tc, int inT, int t0)
{
    const int t = threadIdx.x;
    const int g = t >> 1;
    const int s = t & 1;
    constexpr int KH = K / 2;        // floats per thread
    constexpr int NQ = KH / 4;       // float4 per thread

    float4 wv[NQ];
    {
        const float4* wp = (const float4*)(w + (size_t)g * K + s * KH);
        #pragma unroll
        for (int q = 0; q < NQ; q++) wv[q] = wp[q];
    }
    const float bias = b_a[g] + b_b[g];

    __shared__ __align__(16) float rowbuf[2][K];

    const int nrows = BB * Tc;
    for (int r = blockIdx.x * 2; r < nrows; r += gridDim.x * 2) {
        // stage 2 input rows
        if (t < 2 * K) {
            const int rr = t / K, i = t % K;
            const int rowid = r + rr;
            const int b = rowid >> log2Tc;
            const int tl = rowid & (Tc - 1);
            rowbuf[rr][i] = in[((size_t)b * inT + t0 + tl) * K + i];
        }
        __syncthreads();

        float acc0 = 0.0f, acc1 = 0.0f;
        const float4* i0 = (const float4*)(&rowbuf[0][s * KH]);
        const float4* i1 = (const float4*)(&rowbuf[1][s * KH]);
        #pragma unroll
        for (int q = 0; q < NQ; q++) {
            const float4 w4 = wv[q];
            const float4 a0 = i0[q];
            const float4 a1 = i1[q];
            acc0 += w4.x * a0.x + w4.y * a0.y + w4.z * a0.z + w4.w * a0.w;
            acc1 += w4.x * a1.x + w4.y * a1.y + w4.z * a1.z + w4.w * a1.w;
        }
        acc0 += __shfl_xor(acc0, 1);
        acc1 += __shfl_xor(acc1, 1);
        if (s == 0) {
            xp[(size_t)r * G4 + g]       = acc0 + bias;
            xp[(size_t)(r + 1) * G4 + g] = acc1 + bias;
        }
        __syncthreads();
    }
}

// ---------------------------------------------------------------------------
// Recurrent scan (used for both layers): gates = xp_t + h_{t-1} @ W_hh^T.
// One block = 2 batch rows. 1024 threads: (gate g = t>>1, half s = t&1),
// 64 weight floats per thread. h in LDS (broadcast reads), c in registers of
// threads 0..255. Optionally stores h每step (layer 1 feeding layer 2).
// ---------------------------------------------------------------------------
__global__ __launch_bounds__(1024, 1) void scan_kernel(
    const float* __restrict__ xp, const float* __restrict__ w_hh,
    float* __restrict__ hs, float* __restrict__ cs,
    float* __restrict__ outc, int Tc, int first, int store_out)
{
    const int t = threadIdx.x;
    const int g = t >> 1;
    const int s = t & 1;
    const int r0 = blockIdx.x * 2;

    __shared__ __align__(16) float hbuf[2][HH];
    __shared__ __align__(16) float abuf[2][G4];

    float4 wv[16];
    {
        const float4* wp = (const float4*)(w_hh + (size_t)g * HH + s * 64);
        #pragma unroll
        for (int q = 0; q < 16; q++) wv[q] = wp[q];
    }

    const int row = t >> 7, j = t & 127;   // meaningful for t < 256
    float c = 0.0f;
    if (t < 256) {
        const int b = r0 + row;
        if (first) {
            hbuf[row][j] = 0.0f;
        } else {
            c = cs[b * HH + j];
            hbuf[row][j] = hs[b * HH + j];
        }
    }
    __syncthreads();

    for (int tl = 0; tl < Tc; tl++) {
        // xp values (uniform per lane pair; even lane consumes after combine)
        const float xv0 = xp[((size_t)(r0 + 0) * Tc + tl) * G4 + g];
        const float xv1 = xp[((size_t)(r0 + 1) * Tc + tl) * G4 + g];

        float acc0 = 0.0f, acc1 = 0.0f;
        const float4* h0 = (const float4*)(&hbuf[0][s * 64]);
        const float4* h1 = (const float4*)(&hbuf[1][s * 64]);
        #pragma unroll
        for (int q = 0; q < 16; q++) {
            const float4 w4 = wv[q];
            const float4 a0 = h0[q];
            const float4 a1 = h1[q];
            acc0 += w4.x * a0.x + w4.y * a0.y + w4.z * a0.z + w4.w * a0.w;
            acc1 += w4.x * a1.x + w4.y * a1.y + w4.z * a1.z + w4.w * a1.w;
        }
        acc0 += __shfl_xor(acc0, 1);
        acc1 += __shfl_xor(acc1, 1);

        if (s == 0) {
            const float p0 = acc0 + xv0;
            const float p1 = acc1 + xv1;
            const int type = g >> 7;  // 0:i 1:f 2:g 3:o
            abuf[0][g] = (type == 2) ? tanhfast(p0) : sigf(p0);
            abuf[1][g] = (type == 2) ? tanhfast(p1) : sigf(p1);
        }
        __syncthreads();   // abuf ready; also protects hbuf before overwrite

        if (t < 256) {
            const float iv = abuf[row][j];
            const float fv = abuf[row][128 + j];
            const float gv = abuf[row][256 + j];
            const float ov = abuf[row][384 + j];
            c = fv * c + iv * gv;
            const float h = ov * tanhfast(c);
            hbuf[row][j] = h;
            if (store_out)
                outc[((size_t)(r0 + row) * Tc + tl) * HH + j] = h;
        }
        __syncthreads();   // hbuf ready for next step
    }

    if (t < 256) {
        const int b = r0 + row;
        cs[b * HH + j] = c;
        hs[b * HH + j] = hbuf[row][j];
    }
}

// ---------------------------------------------------------------------------
// logits = h2_last @ w_fc^T + b_fc; sigmoid.
// ---------------------------------------------------------------------------
__global__ void final_kernel(const float* __restrict__ h2s,
                             const float* __restrict__ w_fc,
                             const float* __restrict__ b_fc,
                             float* __restrict__ out)
{
    const int idx = blockIdx.x * blockDim.x + threadIdx.x;
    if (idx >= BB * NCLS) return;
    const int b = idx / NCLS, cls = idx % NCLS;
    const float* h = h2s + (size_t)b * HH;
    const float* w = w_fc + (size_t)cls * HH;
    float acc = b_fc[cls];
    #pragma unroll 8
    for (int k = 0; k < HH; k++) acc += h[k] * w[k];
    out[idx] = sigf(acc);
}

extern "C" void kernel_launch(void* const* d_in, const int* in_sizes, int n_in,
                              void* d_out, int out_size, void* d_ws, size_t ws_size,
                              hipStream_t stream)
{
    const float* x     = (const float*)d_in[0];
    const float* w1_ih = (const float*)d_in[1];
    const float* w1_hh = (const float*)d_in[2];
    const float* b1_ih = (const float*)d_in[3];
    const float* b1_hh = (const float*)d_in[4];
    const float* w2_ih = (const float*)d_in[5];
    const float* w2_hh = (const float*)d_in[6];
    const float* b2_ih = (const float*)d_in[7];
    const float* b2_hh = (const float*)d_in[8];
    const float* w_fc  = (const float*)d_in[9];
    const float* b_fc  = (const float*)d_in[10];
    float* out = (float*)d_out;

    // workspace layout: [h1|c1|h2|c2 | out1_chunk | xp_chunk(shared L1/L2)]
    char* ws = (char*)d_ws;
    const size_t state_bytes = (size_t)BB * HH * sizeof(float);   // 256 KB each
    float* h1s = (float*)ws; ws += state_bytes;
    float* c1s = (float*)ws; ws += state_bytes;
    float* h2s = (float*)ws; ws += state_bytes;
    float* c2s = (float*)ws; ws += state_bytes;

    // footprint(Tc) = 4*state + BB*Tc*HH*4 (out1c) + BB*Tc*G4*4 (xpc)
    int Tc = 64;
    while (Tc > 4 &&
           4 * state_bytes + (size_t)BB * Tc * (HH + G4) * sizeof(float) > ws_size)
        Tc >>= 1;
    int log2Tc = __builtin_ctz(Tc);

    float* out1c = (float*)ws; ws += (size_t)BB * Tc * HH * sizeof(float);
    float* xpc   = (float*)ws;   // reused for layer-1 and layer-2 projections

    const int nch = TT / Tc;
    for (int ci = 0; ci < nch; ci++) {
        // layer-1 input projection for this chunk: rows of x
        xp_kernel<FF><<<256, 1024, 0, stream>>>(x, w1_ih, b1_ih, b1_hh,
                                                xpc, Tc, log2Tc, TT, ci * Tc);
        // layer-1 recurrence (stores h stream for layer 2)
        scan_kernel<<<256, 1024, 0, stream>>>(xpc, w1_hh, h1s, c1s,
                                              out1c, Tc, ci == 0, 1);
        // layer-2 input projection (overwrites xpc; scan1 is done reading it)
        xp_kernel<HH><<<256, 1024, 0, stream>>>(out1c, w2_ih, b2_ih, b2_hh,
                                                xpc, Tc, log2Tc, Tc, 0);
        // layer-2 recurrence (state only)
        scan_kernel<<<256, 1024, 0, stream>>>(xpc, w2_hh, h2s, c2s,
                                              nullptr, Tc, ci == 0, 0);
    }
    final_kernel<<<(BB * NCLS + 255) / 256, 256, 0, stream>>>(h2s, w_fc, b_fc, out);
}

// Round 3
// 1244.906 us; speedup vs baseline: 12.4284x; 3.6666x over previous
//
#include <hip/hip_runtime.h>

#define BB 512   // batch
#define TT 512   // time
#define FF 64    // layer-1 input width
#define HH 128   // hidden
#define G4 512   // 4*H gates
#define NCLS 10
#define WT 64    // x-window steps staged in LDS

typedef __attribute__((ext_vector_type(8))) short short8;
typedef __attribute__((ext_vector_type(4))) float f32x4;

__device__ __forceinline__ float sigf(float x) { return 1.0f / (1.0f + __expf(-x)); }
__device__ __forceinline__ float tanhfast(float x) { return 2.0f / (1.0f + __expf(-2.0f * x)) - 1.0f; }
__device__ __forceinline__ unsigned short f2bf(float f) {
    union { float f; unsigned u; } v; v.f = f;
    unsigned r = v.u + 0x7FFFu + ((v.u >> 16) & 1u);   // RNE
    return (unsigned short)(r >> 16);
}

// ---------------------------------------------------------------------------
// Fused LSTM layer scan with MFMA. One block = 2 batch rows, 1024 threads =
// 16 waves. Wave w owns gates [w*32, w*32+32) (2 N-tiles of 16).
// Per step: gates = bias + [x_t | h_{t-1}] @ [W_ih; W_hh]^T  via
// mfma_f32_16x16x32_bf16, K = XW + 128 (192 layer1 / 256 layer2).
// B (weights, bf16) stationary in VGPRs. A rows 0,1 = the 2 batch rows
// (lanes m>=2 read duplicate data via r=l&1 -> compute ignored C rows).
// x-stream staged in LDS bf16 in windows of WT steps; h in LDS bf16.
// State (c fp32, h fp32) in registers of threads 0..255.
// ---------------------------------------------------------------------------
template<int XW, bool IN_BF16, bool STORE>
__global__ __launch_bounds__(1024, 1) void scan_mfma(
    const void* __restrict__ xin, size_t strideB, int tbase,
    const float* __restrict__ w_ih, const float* __restrict__ w_hh,
    const float* __restrict__ b_ih, const float* __restrict__ b_hh,
    unsigned short* __restrict__ out1c,
    float* __restrict__ hs, float* __restrict__ cs,
    int Tc, int first)
{
    const int tid = threadIdx.x;
    const int w   = tid >> 6;
    const int l   = tid & 63;
    const int lm  = l & 15;    // A-row m / B-col n / C-col n
    const int kb  = l >> 4;    // k-block within tile
    const int rA  = l & 1;     // A source row (m>=2 duplicates rows 0/1)
    const int gbase = w * 32;
    const int r0  = blockIdx.x * 2;
    constexpr int KC = XW + HH;
    constexpr int KT = KC / 32;

    __shared__ __align__(16) unsigned short xwin[2][WT][XW];
    __shared__ __align__(16) unsigned short hb[2][HH];
    __shared__ __align__(16) float abuf[2][G4];

    // --- stationary B fragments (bf16) + bias ---
    short8 bf[2][KT];
    float bv[2];
    #pragma unroll
    for (int nt = 0; nt < 2; nt++) {
        const int g = gbase + nt * 16 + lm;
        bv[nt] = b_ih[g] + b_hh[g];
        #pragma unroll
        for (int kt = 0; kt < KT; kt++) {
            const int k0 = kt * 32 + kb * 8;
            const float* src = (k0 < XW) ? (w_ih + (size_t)g * XW + k0)
                                         : (w_hh + (size_t)g * HH + (k0 - XW));
            short8 bb;
            #pragma unroll
            for (int j = 0; j < 8; j++) bb[j] = (short)f2bf(src[j]);
            bf[nt][kt] = bb;
        }
    }
    const int type = gbase >> 7;   // 0:i 1:f 2:g 3:o (wave-uniform)

    // --- state init ---
    const int srow = tid >> 7, sj = tid & 127;   // threads 0..255
    float c = 0.0f, h = 0.0f;
    if (tid < 256) {
        if (first) {
            hb[srow][sj] = 0;
        } else {
            c = cs[(r0 + srow) * HH + sj];
            h = hs[(r0 + srow) * HH + sj];
            hb[srow][sj] = f2bf(h);
        }
    }
    __syncthreads();

    for (int tl = 0; tl < Tc; tl++) {
        // ---- stage x window every WT steps ----
        if ((tl & (WT - 1)) == 0) {
            if (IN_BF16) {
                const unsigned short* xs = (const unsigned short*)xin;
                const int NV = 2 * WT * XW / 8;        // uint4 chunks
                for (int e = tid; e < NV; e += 1024) {
                    const int r   = e / (WT * XW / 8);
                    const int rem = e - r * (WT * XW / 8);
                    const int tt  = rem / (XW / 8);
                    const int k8  = rem - tt * (XW / 8);
                    const uint4* s = (const uint4*)(xs + (size_t)(r0 + r) * strideB
                                                   + (size_t)(tbase + tl + tt) * XW + k8 * 8);
                    *(uint4*)&xwin[r][tt][k8 * 8] = *s;
                }
            } else {
                const float* xs = (const float*)xin;
                const int NV = 2 * WT * XW / 4;        // float4 chunks
                for (int e = tid; e < NV; e += 1024) {
                    const int r   = e / (WT * XW / 4);
                    const int rem = e - r * (WT * XW / 4);
                    const int tt  = rem / (XW / 4);
                    const int k4  = rem - tt * (XW / 4);
                    const float4 v = *(const float4*)(xs + (size_t)(r0 + r) * strideB
                                                     + (size_t)(tbase + tl + tt) * XW + k4 * 4);
                    const unsigned lo = (unsigned)f2bf(v.x) | ((unsigned)f2bf(v.y) << 16);
                    const unsigned hi = (unsigned)f2bf(v.z) | ((unsigned)f2bf(v.w) << 16);
                    uint2 p; p.x = lo; p.y = hi;
                    *(uint2*)&xwin[r][tt][k4 * 4] = p;
                }
            }
            __syncthreads();
        }
        const int tloc = tl & (WT - 1);

        // ---- MFMA: gates = bias + [x|h] @ Wcat^T ----
        f32x4 acc0 = {bv[0], bv[0], bv[0], bv[0]};
        f32x4 acc1 = {bv[1], bv[1], bv[1], bv[1]};
        #pragma unroll
        for (int kt = 0; kt < KT; kt++) {
            const int k0 = kt * 32 + kb * 8;
            const unsigned short* ap = (k0 < XW) ? &xwin[rA][tloc][k0]
                                                 : &hb[rA][k0 - XW];
            const short8 a = *(const short8*)ap;
            acc0 = __builtin_amdgcn_mfma_f32_16x16x32_bf16(a, bf[0][kt], acc0, 0, 0, 0);
            acc1 = __builtin_amdgcn_mfma_f32_16x16x32_bf16(a, bf[1][kt], acc1, 0, 0, 0);
        }

        // ---- epilogue: rows 0,1 live in lanes 0..15, regs 0,1 ----
        if (l < 16) {
            const float p00 = acc0[0], p01 = acc0[1];
            const float p10 = acc1[0], p11 = acc1[1];
            float a00, a01, a10, a11;
            if (type == 2) {
                a00 = tanhfast(p00); a01 = tanhfast(p01);
                a10 = tanhfast(p10); a11 = tanhfast(p11);
            } else {
                a00 = sigf(p00); a01 = sigf(p01);
                a10 = sigf(p10); a11 = sigf(p11);
            }
            abuf[0][gbase + lm]      = a00;
            abuf[1][gbase + lm]      = a01;
            abuf[0][gbase + 16 + lm] = a10;
            abuf[1][gbase + 16 + lm] = a11;
        }
        __syncthreads();

        // ---- state update ----
        if (tid < 256) {
            const float iv = abuf[srow][sj];
            const float fv = abuf[srow][128 + sj];
            const float gv = abuf[srow][256 + sj];
            const float ov = abuf[srow][384 + sj];
            c = fv * c + iv * gv;
            h = ov * tanhfast(c);
            const unsigned short hbf = f2bf(h);
            hb[srow][sj] = hbf;
            if (STORE)
                out1c[((size_t)(r0 + srow) * Tc + tl) * HH + sj] = hbf;
        }
        __syncthreads();
    }

    if (tid < 256) {
        cs[(r0 + srow) * HH + sj] = c;
        hs[(r0 + srow) * HH + sj] = h;
    }
}

// ---------------------------------------------------------------------------
// logits = h2_last @ w_fc^T + b_fc; sigmoid.
// ---------------------------------------------------------------------------
__global__ void final_kernel(const float* __restrict__ h2s,
                             const float* __restrict__ w_fc,
                             const float* __restrict__ b_fc,
                             float* __restrict__ out)
{
    const int idx = blockIdx.x * blockDim.x + threadIdx.x;
    if (idx >= BB * NCLS) return;
    const int b = idx / NCLS, cls = idx % NCLS;
    const float* hp = h2s + (size_t)b * HH;
    const float* wp = w_fc + (size_t)cls * HH;
    float acc = b_fc[cls];
    #pragma unroll 8
    for (int k = 0; k < HH; k++) acc += hp[k] * wp[k];
    out[idx] = sigf(acc);
}

extern "C" void kernel_launch(void* const* d_in, const int* in_sizes, int n_in,
                              void* d_out, int out_size, void* d_ws, size_t ws_size,
                              hipStream_t stream)
{
    const float* x     = (const float*)d_in[0];
    const float* w1_ih = (const float*)d_in[1];
    const float* w1_hh = (const float*)d_in[2];
    const float* b1_ih = (const float*)d_in[3];
    const float* b1_hh = (const float*)d_in[4];
    const float* w2_ih = (const float*)d_in[5];
    const float* w2_hh = (const float*)d_in[6];
    const float* b2_ih = (const float*)d_in[7];
    const float* b2_hh = (const float*)d_in[8];
    const float* w_fc  = (const float*)d_in[9];
    const float* b_fc  = (const float*)d_in[10];
    float* out = (float*)d_out;

    // workspace: [h1|c1|h2|c2 fp32 states | out1 chunk bf16]
    char* ws = (char*)d_ws;
    const size_t state_bytes = (size_t)BB * HH * sizeof(float);   // 256 KB each
    float* h1s = (float*)ws; ws += state_bytes;
    float* c1s = (float*)ws; ws += state_bytes;
    float* h2s = (float*)ws; ws += state_bytes;
    float* c2s = (float*)ws; ws += state_bytes;

    // Tc=512 needs 1 MB + 64 MB; halve until it fits (WT=64 must divide Tc)
    int Tc = 512;
    while (Tc > 64 &&
           4 * state_bytes + (size_t)BB * Tc * HH * sizeof(unsigned short) > ws_size)
        Tc >>= 1;

    unsigned short* out1c = (unsigned short*)ws;

    const int nch = TT / Tc;
    for (int ci = 0; ci < nch; ci++) {
        // layer 1: x fp32 [BB][TT][FF], K = 64+128
        scan_mfma<FF, false, true><<<256, 1024, 0, stream>>>(
            (const void*)x, (size_t)TT * FF, ci * Tc,
            w1_ih, w1_hh, b1_ih, b1_hh, out1c, h1s, c1s, Tc, ci == 0);
        // layer 2: out1 bf16 [BB][Tc][HH], K = 128+128
        scan_mfma<HH, true, false><<<256, 1024, 0, stream>>>(
            (const void*)out1c, (size_t)Tc * HH, 0,
            w2_ih, w2_hh, b2_ih, b2_hh, nullptr, h2s, c2s, Tc, ci == 0);
    }
    final_kernel<<<(BB * NCLS + 255) / 256, 256, 0, stream>>>(h2s, w_fc, b_fc, out);
}